// Round 2
// baseline (34.908 us; speedup 1.0000x reference)
//
#include <hip/hip_runtime.h>
#include <hip/hip_bf16.h>
#include <stdint.h>

// GridMask, MODE=0: out = x * mask(b,h,w), broadcast over C=3.
// mask==0 iff ((OFF+h - st_h) mod d) < l  OR  ((OFF+w - st_w) mod d) < l
//   d = 96 + d_raw[b], l = ceil(d/2), st_h = st_h_raw[b] % d, st_w = st_w_raw[b] % d
// HH = ceil(sqrt(512^2+512^2)) = 725, OFF_H = OFF_W = (725-512)/2 = 106.
//
// R2 structure: one block per 8 consecutive rows of one image (grid 2048,
// block 384). Column mask per thread computed once, reused for all 8 rows;
// row phase ty advances by +1 mod d per row (no division in the loop).

#define BB 32
#define HH_ 512
#define WW 512
#define CC 3
#define D1_ 96
#define OFFC 106
#define ROW_FLOATS (WW * CC)     // 1536 floats per row, 6144 B (16B aligned)
#define RPB 8                    // rows per block (divides 512 -> same image)

__global__ __launch_bounds__(384) void gridmask_kernel(
    const float* __restrict__ x,
    const int* __restrict__ d_raw,
    const int* __restrict__ st_h_raw,
    const int* __restrict__ st_w_raw,
    float* __restrict__ out)
{
    const int row0 = blockIdx.x * RPB;      // first row this block owns
    const int b = row0 >> 9;                // / 512 (all RPB rows same image)
    const int h0 = row0 & 511;

    // Per-batch params (wave-uniform). One u32 division for the magic
    // reciprocal; every mod after that is mul-based and exact for t < 2^32/d.
    const uint32_t d = (uint32_t)(D1_ + d_raw[b]);      // 96..319
    const uint32_t l = (d + 1u) >> 1;                   // ceil(d * 0.5)
    const uint32_t M = 0xFFFFFFFFu / d + 1u;            // ceil(2^32 / d)

    uint32_t sh = (uint32_t)st_h_raw[b];
    sh -= (uint32_t)(((uint64_t)sh * M) >> 32) * d;     // st_h_raw % d
    uint32_t sw = (uint32_t)st_w_raw[b];
    sw -= (uint32_t)(((uint64_t)sw * M) >> 32) * d;     // st_w_raw % d

    // Row stripe phase for h0 (uniform per block). +4d keeps arg positive.
    uint32_t ty = (uint32_t)(OFFC + h0) + 4u * d - sh;
    ty -= (uint32_t)(((uint64_t)ty * M) >> 32) * d;     // in [0, d)

    // This thread's 4 consecutive floats within a row: span <= 2 pixels.
    const int e0 = (int)threadIdx.x * 4;                // 0..1532
    const int w0 = e0 / 3;                              // first pixel column

    uint32_t t0 = (uint32_t)(OFFC + w0) + 4u * d - sw;
    t0 -= (uint32_t)(((uint64_t)t0 * M) >> 32) * d;     // in [0, d)
    uint32_t t1 = t0 + 1u;                              // column w0+1, wrapped
    if (t1 >= d) t1 -= d;
    const float cm0 = (t0 < l) ? 0.0f : 1.0f;
    const float cm1 = (t1 < l) ? 0.0f : 1.0f;

    size_t base = (size_t)row0 * ROW_FLOATS + (size_t)e0;

#pragma unroll
    for (int r = 0; r < RPB; ++r) {
        float4 v = *(const float4*)(x + base);
        const float rmask = (ty < l) ? 0.0f : 1.0f;
        const float m0 = rmask * cm0;
        const float m1 = rmask * cm1;

        float rr[4] = {v.x, v.y, v.z, v.w};
#pragma unroll
        for (int j = 0; j < 4; ++j) {
            const int w = (e0 + j) / 3;                 // const-div, folds
            rr[j] *= (w == w0) ? m0 : m1;
        }
        *(float4*)(out + base) = make_float4(rr[0], rr[1], rr[2], rr[3]);

        // next row: phase advances by exactly 1 (mod d)
        ++ty;
        if (ty >= d) ty = 0;
        base += ROW_FLOATS;
    }
}

extern "C" void kernel_launch(void* const* d_in, const int* in_sizes, int n_in,
                              void* d_out, int out_size, void* d_ws, size_t ws_size,
                              hipStream_t stream) {
    const float* x        = (const float*)d_in[0];
    const int* d_raw      = (const int*)d_in[1];
    const int* st_h_raw   = (const int*)d_in[2];
    const int* st_w_raw   = (const int*)d_in[3];
    float* out            = (float*)d_out;

    const int n_blocks = (BB * HH_) / RPB;  // 2048 blocks, 8 rows each
    gridmask_kernel<<<n_blocks, 384, 0, stream>>>(x, d_raw, st_h_raw, st_w_raw, out);
}

// Round 9
// 33.754 us; speedup vs baseline: 1.0342x; 1.0342x over previous
//
#include <hip/hip_runtime.h>
#include <hip/hip_bf16.h>
#include <stdint.h>

// GridMask, MODE=0: out = x * mask(b,h,w), broadcast over C=3.
// mask==0 iff ((OFF+h - st_h) mod d) < l  OR  ((OFF+w - st_w) mod d) < l
//   d = 96 + d_raw[b], l = ceil(d/2), st_h = st_h_raw[b] % d, st_w = st_w_raw[b] % d
// HH = ceil(sqrt(512^2+512^2)) = 725, OFF_H = OFF_W = (725-512)/2 = 106.
//
// R9 == R4..R8 (container unresponsive five rounds running): R1 geometry
// (one block per row) + non-temporal stores via native clang ext_vector_type.
// Goal: keep the 100.7 MB input L3-resident across replays by streaming the
// write-only output past the caches -> HBM traffic ~ write-only.

#define BB 32
#define HH_ 512
#define WW 512
#define CC 3
#define D1_ 96
#define OFFC 106
#define ROW_FLOATS (WW * CC)   // 1536 floats per (b,h) row, 6144 B (16B aligned)

typedef float f32x4 __attribute__((ext_vector_type(4)));

__global__ __launch_bounds__(384) void gridmask_kernel(
    const float* __restrict__ x,
    const int* __restrict__ d_raw,
    const int* __restrict__ st_h_raw,
    const int* __restrict__ st_w_raw,
    float* __restrict__ out)
{
    const int row_id = blockIdx.x;          // 0 .. B*H-1, one block per image row
    const int b = row_id >> 9;              // / 512
    const int h = row_id & 511;

    // Per-batch params (wave-uniform). One u32 division for the magic
    // reciprocal; every mod after that is mul-based and exact for t < 2^32/d.
    const uint32_t d = (uint32_t)(D1_ + d_raw[b]);      // 96..319
    const uint32_t l = (d + 1u) >> 1;                   // ceil(d * 0.5)
    const uint32_t M = 0xFFFFFFFFu / d + 1u;            // ceil(2^32 / d)

    uint32_t sh = (uint32_t)st_h_raw[b];
    sh -= (uint32_t)(((uint64_t)sh * M) >> 32) * d;     // st_h_raw % d
    uint32_t sw = (uint32_t)st_w_raw[b];
    sw -= (uint32_t)(((uint64_t)sw * M) >> 32) * d;     // st_w_raw % d

    // Row stripe test (uniform per block). +4d keeps the argument positive.
    uint32_t ty = (uint32_t)(OFFC + h) + 4u * d - sh;
    ty -= (uint32_t)(((uint64_t)ty * M) >> 32) * d;     // Python-style mod
    const float rmask = (ty < l) ? 0.0f : 1.0f;

    // This thread's 4 consecutive floats within the row: span <= 2 pixels.
    const int e0 = (int)threadIdx.x * 4;                // 0..1532
    const int w0 = e0 / 3;                              // first pixel column

    uint32_t t0 = (uint32_t)(OFFC + w0) + 4u * d - sw;
    t0 -= (uint32_t)(((uint64_t)t0 * M) >> 32) * d;     // in [0, d)
    uint32_t t1 = t0 + 1u;                              // column w0+1, with wrap
    if (t1 >= d) t1 -= d;
    const float cm0 = rmask * ((t0 < l) ? 0.0f : 1.0f);
    const float cm1 = rmask * ((t1 < l) ? 0.0f : 1.0f);

    const size_t base = (size_t)row_id * ROW_FLOATS + (size_t)e0;
    f32x4 v = *(const f32x4*)(x + base);                // cached load (L3-resident)

#pragma unroll
    for (int j = 0; j < 4; ++j) {
        const int w = (e0 + j) / 3;                     // const-div -> magic mul
        v[j] *= (w == w0) ? cm0 : cm1;
    }
    // Streaming store: don't allocate the write-only output in L2/L3.
    __builtin_nontemporal_store(v, (f32x4*)(out + base));
}

extern "C" void kernel_launch(void* const* d_in, const int* in_sizes, int n_in,
                              void* d_out, int out_size, void* d_ws, size_t ws_size,
                              hipStream_t stream) {
    const float* x        = (const float*)d_in[0];
    const int* d_raw      = (const int*)d_in[1];
    const int* st_h_raw   = (const int*)d_in[2];
    const int* st_w_raw   = (const int*)d_in[3];
    float* out            = (float*)d_out;

    const int n_rows = BB * HH_;            // 16384 blocks, one per (b,h) row
    gridmask_kernel<<<n_rows, 384, 0, stream>>>(x, d_raw, st_h_raw, st_w_raw, out);
}

// Round 10
// 20.521 us; speedup vs baseline: 1.7011x; 1.6449x over previous
//
#include <hip/hip_runtime.h>
#include <hip/hip_bf16.h>
#include <stdint.h>

// GridMask, MODE=0: out = x * mask(b,h,w), broadcast over C=3.
// mask==0 iff ((OFF+h - st_h) mod d) < l  OR  ((OFF+w - st_w) mod d) < l
//   d = 96 + d_raw[b], l = ceil(d/2), st_h = st_h_raw[b] % d, st_w = st_w_raw[b] % d
// HH = ceil(sqrt(512^2+512^2)) = 725, OFF_H = OFF_W = (725-512)/2 = 106.
//
// R10: LOAD ELISION. ~75% of outputs are zero (l/d ~= 0.5 both axes): zeroed
// rows skip ALL loads (block-uniform branch); within kept rows, lanes fully
// inside a zero column-stripe never issue their load, so interior cache lines
// of each 576-1920 B stripe are never fetched. Read traffic ~100 -> ~25 MB.
// Writes (100.7 MB incl. zeros) are mandatory; keep nt-stores (neutral, but
// write-only data has no reuse).

#define BB 32
#define HH_ 512
#define WW 512
#define CC 3
#define D1_ 96
#define OFFC 106
#define ROW_FLOATS (WW * CC)   // 1536 floats per (b,h) row, 6144 B (16B aligned)

typedef float f32x4 __attribute__((ext_vector_type(4)));

__global__ __launch_bounds__(384) void gridmask_kernel(
    const float* __restrict__ x,
    const int* __restrict__ d_raw,
    const int* __restrict__ st_h_raw,
    const int* __restrict__ st_w_raw,
    float* __restrict__ out)
{
    const int row_id = blockIdx.x;          // 0 .. B*H-1, one block per image row
    const int b = row_id >> 9;              // / 512
    const int h = row_id & 511;

    // Per-batch params (wave-uniform). One u32 division for the magic
    // reciprocal; every mod after that is mul-based and exact for t < 2^32/d.
    const uint32_t d = (uint32_t)(D1_ + d_raw[b]);      // 96..319
    const uint32_t l = (d + 1u) >> 1;                   // ceil(d * 0.5)
    const uint32_t M = 0xFFFFFFFFu / d + 1u;            // ceil(2^32 / d)

    uint32_t sh = (uint32_t)st_h_raw[b];
    sh -= (uint32_t)(((uint64_t)sh * M) >> 32) * d;     // st_h_raw % d
    uint32_t sw = (uint32_t)st_w_raw[b];
    sw -= (uint32_t)(((uint64_t)sw * M) >> 32) * d;     // st_w_raw % d

    const int e0 = (int)threadIdx.x * 4;                // 0..1532
    const size_t base = (size_t)row_id * ROW_FLOATS + (size_t)e0;

    // Row stripe test (uniform per block). +4d keeps the argument positive.
    uint32_t ty = (uint32_t)(OFFC + h) + 4u * d - sh;
    ty -= (uint32_t)(((uint64_t)ty * M) >> 32) * d;     // Python-style mod

    if (ty < l) {
        // Entire row zeroed: write zeros, issue NO loads (block-uniform).
        f32x4 z = {0.0f, 0.0f, 0.0f, 0.0f};
        __builtin_nontemporal_store(z, (f32x4*)(out + base));
        return;
    }

    // Column stripe test for this thread's <=2 pixels.
    const int w0 = e0 / 3;                              // first pixel column
    uint32_t t0 = (uint32_t)(OFFC + w0) + 4u * d - sw;
    t0 -= (uint32_t)(((uint64_t)t0 * M) >> 32) * d;     // in [0, d)
    uint32_t t1 = t0 + 1u;                              // column w0+1, with wrap
    if (t1 >= d) t1 -= d;
    const bool keep0 = (t0 >= l);
    const bool keep1 = (t1 >= l);

    f32x4 v = {0.0f, 0.0f, 0.0f, 0.0f};
    if (keep0 | keep1) {
        // At least one covered pixel survives: load and mask.
        v = *(const f32x4*)(x + base);
        const float cm0 = keep0 ? 1.0f : 0.0f;
        const float cm1 = keep1 ? 1.0f : 0.0f;
#pragma unroll
        for (int j = 0; j < 4; ++j) {
            const int w = (e0 + j) / 3;                 // const-div -> magic mul
            v[j] *= (w == w0) ? cm0 : cm1;
        }
    }
    // Lanes fully inside a zero stripe fall through with v = 0 and never
    // touch x: interior cache lines of the stripe are never fetched.
    __builtin_nontemporal_store(v, (f32x4*)(out + base));
}

extern "C" void kernel_launch(void* const* d_in, const int* in_sizes, int n_in,
                              void* d_out, int out_size, void* d_ws, size_t ws_size,
                              hipStream_t stream) {
    const float* x        = (const float*)d_in[0];
    const int* d_raw      = (const int*)d_in[1];
    const int* st_h_raw   = (const int*)d_in[2];
    const int* st_w_raw   = (const int*)d_in[3];
    float* out            = (float*)d_out;

    const int n_rows = BB * HH_;            // 16384 blocks, one per (b,h) row
    gridmask_kernel<<<n_rows, 384, 0, stream>>>(x, d_raw, st_h_raw, st_w_raw, out);
}